// Round 2
// baseline (802.749 us; speedup 1.0000x reference)
//
#include <hip/hip_runtime.h>
#include <math.h>

typedef __attribute__((ext_vector_type(8))) short short8;
typedef __attribute__((ext_vector_type(4))) float floatx4;

__device__ __forceinline__ float sig(float z) { return 1.0f / (1.0f + __expf(-z)); }

__device__ __forceinline__ unsigned short f2bf(float f) {
    unsigned u = __float_as_uint(f);
    u = (u + 0x7FFFu + ((u >> 16) & 1u)) >> 16;   // RNE
    return (unsigned short)u;
}

// v_cvt_pk_bf16_f32: packs 2 f32 -> 2 bf16 (RNE) in one instruction.
// Identical rounding to f2bf; no builtin on gfx950 so inline asm.
__device__ __forceinline__ unsigned cvtpk_bf16(float lo, float hi) {
    unsigned r;
    asm("v_cvt_pk_bf16_f32 %0, %1, %2" : "=v"(r) : "v"(lo), "v"(hi));
    return r;
}

__device__ __forceinline__ short8 pack8_bf16(const float* v) {
    union { short8 s; unsigned u[4]; } r;
    r.u[0] = cvtpk_bf16(v[0], v[1]);
    r.u[1] = cvtpk_bf16(v[2], v[3]);
    r.u[2] = cvtpk_bf16(v[4], v[5]);
    r.u[3] = cvtpk_bf16(v[6], v[7]);
    return r.s;
}

// All four W1 matrices -> bf16 pre-swizzled MFMA 16x16x32 B-frag order.
// blk = (n>>4)*(H/32) + (k>>5), lane = ((k>>3)&3)*16 + (n&15), j = k&7.
// NOTE: this is the per-element version (one 2B store per thread). A coalesced
// wave-per-fragment-block rewrite (prev session R13) caused intermittent
// post-timing divergence — keep this 12/12-passing version (~4 us).
__global__ void convert_all(const float* __restrict__ s0, const float* __restrict__ s1,
                            const float* __restrict__ s2, const float* __restrict__ s3,
                            unsigned short* __restrict__ ws) {
    int idx = blockIdx.x * 256 + threadIdx.x;          // 0 .. 458751
    const float* src; unsigned short* dst; int H, logH, local;
    if (idx < 262144) { src = s0; dst = ws; H = 512; logH = 9; local = idx; }
    else {
        int r = idx - 262144; int m = r >> 16; local = r & 65535;
        H = 256; logH = 8;
        src = (m == 0) ? s1 : (m == 1) ? s2 : s3;
        dst = ws + 262144 + m * 65536;
    }
    int n = local & (H - 1), k = local >> logH;
    int KT = H >> 5;
    int blk = (n >> 4) * KT + (k >> 5);
    int lane = ((k >> 3) & 3) * 16 + (n & 15);
    int j = k & 7;
    dst[(blk * 64 + lane) * 8 + j] = f2bf(src[local]);
}

struct PosS {
    float B0[512], B1[512], W2[1536];
    float Q[8][8], Qd[8][8];
    float Acc[4][64][3], Sum[64][3];
};
struct RpyS {
    float B0[256], B1[256], W2[512];
    float Q[16][8], Qd[16][8];
    float Acc[4][128][2], Sum[128][2];
};

// Fused kernel. R1/R2: K-split the layer-1 A-tile into two 32KB halves
// (L0 half -> barrier -> MFMA half, acc carried across) so dynamic LDS
// drops 64KB -> 32KB and occupancy rises 2 -> 3 blocks/CU; layer-0 bf16
// conversion now v_cvt_pk_bf16_f32 (1 instr / 2 values, same RNE).
// 5120 blocks; role r5<2 -> pos tile (8 samples), r5>=2 -> rpy head (16 samples).
// XCD-colocated remap: all 5 roles of sample-group g land on XCD g%8 so the four
// co-writers of each output cache line share one L2 (verified: WRITE 38->21 MB).
__global__ __launch_bounds__(256, 3)
void fused_mfma(const float* __restrict__ x,
                const float* __restrict__ pW0, const float* __restrict__ pb0,
                const float* __restrict__ pb1,
                const float* __restrict__ pW2, const float* __restrict__ pb2,
                const float* __restrict__ rW0_, const float* __restrict__ rb0_,
                const float* __restrict__ rb1_,
                const float* __restrict__ rW2_, const float* __restrict__ rb2_,
                const float* __restrict__ piW0, const float* __restrict__ pib0,
                const float* __restrict__ pib1,
                const float* __restrict__ piW2, const float* __restrict__ pib2,
                const float* __restrict__ yW0, const float* __restrict__ yb0,
                const float* __restrict__ yb1,
                const float* __restrict__ yW2, const float* __restrict__ yb2,
                const unsigned short* __restrict__ wsBase,
                float* __restrict__ out, int ns)
{
    extern __shared__ unsigned short sA[];      // 32 KB dynamic (one K-half)
    __shared__ union { PosS p; RpyS r; } sU;

    const int tid = threadIdx.x;
    const int xcd  = blockIdx.x & 7;
    const int slot = blockIdx.x >> 3;           // 0..639 within this XCD
    const int gidx = slot / 5, r5 = slot % 5;
    const int g = xcd + (gidx << 3);            // group 0..1023

    const size_t JTOT = (size_t)ns * 18, OUTA = (size_t)ns * 81, JANG = (size_t)ns * 87;
    const floatx4 z4 = {0.f, 0.f, 0.f, 0.f};
    const int w = tid >> 6, lane = tid & 63;
    const int quad = lane >> 4, col = lane & 15;
    const int srcl = lane & 47;

    if (r5 < 2) {
        // ================= POS: 7 -> 512 -> 512 -> 3, 8 samples =================
        const int m0 = (g * 2 + r5) * 8;
        const unsigned short* wsW1 = wsBase;

        for (int i = tid; i < 512;  i += 256) { sU.p.B0[i] = pb0[i]; sU.p.B1[i] = pb1[i]; }
        for (int i = tid; i < 1536; i += 256) sU.p.W2[i] = pW2[i];
        if (tid < 112) {
            int m = tid / 14, c = tid % 14;
            float v = x[(m0 + m) * 14 + c];
            if (c < 7) sU.p.Q[m][c] = v; else sU.p.Qd[m][c - 7] = v;
        }
        __syncthreads();

        const float4* W04 = (const float4*)pW0;

        floatx4 acc[4][8];
        #pragma unroll
        for (int rt = 0; rt < 4; rt++)
            #pragma unroll
            for (int ct = 0; ct < 8; ct++) acc[rt][ct] = z4;

        const short8* bbase = (const short8*)wsW1 + (size_t)(w * 8 * 16) * 64 + lane;
        short8 bufA[8], bufB[8];

        #pragma unroll
        for (int hh = 0; hh < 2; ++hh) {
            // ---- layer 0, K-half hh: k8 = hh*32 .. hh*32+31, 1 item/thread ----
            {
                const int s = tid >> 5, k8l = tid & 31, k8 = (hh << 5) | k8l;
                float q[7], w0v[7][8];
                #pragma unroll
                for (int i = 0; i < 7; i++) {
                    q[i] = sU.p.Q[s][i];
                    float4 a = W04[i * 128 + k8 * 2], b4 = W04[i * 128 + k8 * 2 + 1];
                    w0v[i][0]=a.x; w0v[i][1]=a.y; w0v[i][2]=a.z; w0v[i][3]=a.w;
                    w0v[i][4]=b4.x; w0v[i][5]=b4.y; w0v[i][6]=b4.z; w0v[i][7]=b4.w;
                }
                float hv[8], dv[8];
                #pragma unroll
                for (int jj = 0; jj < 8; jj++) {
                    float z = sU.p.B0[k8 * 8 + jj];
                    #pragma unroll
                    for (int i = 0; i < 7; i++) z = fmaf(q[i], w0v[i][jj], z);
                    float h = sig(z);
                    hv[jj] = h; dv[jj] = h - h * h;
                }
                const int ktl = k8l >> 2, kq = k8l & 3, sw = ktl; // sw = (k8>>2)&7
                const int rr0 = s * 8;
                *(short8*)&sA[((rr0 >> 4) * 8 + ktl) * 512 + ((kq * 16 + (rr0 & 15)) ^ sw) * 8]
                    = pack8_bf16(hv);
                #pragma unroll
                for (int i = 0; i < 7; i++) {
                    const int rr = rr0 + 1 + i;
                    float t[8];
                    #pragma unroll
                    for (int jj = 0; jj < 8; jj++) t[jj] = dv[jj] * w0v[i][jj];
                    *(short8*)&sA[((rr >> 4) * 8 + ktl) * 512 + ((kq * 16 + (rr & 15)) ^ sw) * 8]
                        = pack8_bf16(t);
                }
            }
            // prefetch first B-frags of this half (global; independent of sA)
            #pragma unroll
            for (int ct = 0; ct < 8; ++ct) bufA[ct] = bbase[(ct * 16 + hh * 8) * 64];
            __syncthreads();

            for (int kt2 = 0; kt2 < 8; kt2 += 2) {
                #pragma unroll
                for (int ct = 0; ct < 8; ++ct) bufB[ct] = bbase[(ct * 16 + hh * 8 + kt2 + 1) * 64];
                {
                    const int ktl = kt2, sw = ktl;
                    short8 afr[4];
                    #pragma unroll
                    for (int rt = 0; rt < 4; ++rt)
                        afr[rt] = *(const short8*)&sA[(rt * 8 + ktl) * 512 + (lane ^ sw) * 8];
                    #pragma unroll
                    for (int ct = 0; ct < 8; ++ct)
                        #pragma unroll
                        for (int rt = 0; rt < 4; ++rt)
                            acc[rt][ct] = __builtin_amdgcn_mfma_f32_16x16x32_bf16(afr[rt], bufA[ct], acc[rt][ct], 0, 0, 0);
                }
                if (kt2 + 2 < 8) {
                    #pragma unroll
                    for (int ct = 0; ct < 8; ++ct) bufA[ct] = bbase[(ct * 16 + hh * 8 + kt2 + 2) * 64];
                }
                {
                    const int ktl = kt2 + 1, sw = ktl;
                    short8 afr[4];
                    #pragma unroll
                    for (int rt = 0; rt < 4; ++rt)
                        afr[rt] = *(const short8*)&sA[(rt * 8 + ktl) * 512 + (lane ^ sw) * 8];
                    #pragma unroll
                    for (int ct = 0; ct < 8; ++ct)
                        #pragma unroll
                        for (int rt = 0; rt < 4; ++rt)
                            acc[rt][ct] = __builtin_amdgcn_mfma_f32_16x16x32_bf16(afr[rt], bufB[ct], acc[rt][ct], 0, 0, 0);
                }
            }
            if (hh == 0) __syncthreads();   // drain reads before half-1 overwrites sA
        }

        float ep[4][4][3];
        #pragma unroll
        for (int a = 0; a < 4; a++) for (int b = 0; b < 4; b++) for (int c = 0; c < 3; c++) ep[a][b][c] = 0.f;

        #pragma unroll
        for (int ct = 0; ct < 8; ++ct) {
            const int n = w * 128 + ct * 16 + col;
            const float b1n = sU.p.B1[n];
            const float w20 = sU.p.W2[n * 3], w21 = sU.p.W2[n * 3 + 1], w22 = sU.p.W2[n * 3 + 2];
            #pragma unroll
            for (int rt = 0; rt < 4; ++rt) {
                float z2c = __shfl(acc[rt][ct][0], srcl);
                float h2 = sig(z2c + b1n);
                float d2 = h2 - h2 * h2;
                #pragma unroll
                for (int r = 0; r < 4; ++r) {
                    float gg = ((quad & 1) == 0 && r == 0) ? h2 : d2 * acc[rt][ct][r];
                    ep[rt][r][0] = fmaf(gg, w20, ep[rt][r][0]);
                    ep[rt][r][1] = fmaf(gg, w21, ep[rt][r][1]);
                    ep[rt][r][2] = fmaf(gg, w22, ep[rt][r][2]);
                }
            }
        }

        #pragma unroll
        for (int mask = 1; mask <= 8; mask <<= 1)
            #pragma unroll
            for (int a = 0; a < 4; a++)
                #pragma unroll
                for (int b = 0; b < 4; b++)
                    #pragma unroll
                    for (int c = 0; c < 3; c++)
                        ep[a][b][c] += __shfl_xor(ep[a][b][c], mask);
        if (col == 0) {
            #pragma unroll
            for (int rt = 0; rt < 4; ++rt)
                #pragma unroll
                for (int r = 0; r < 4; ++r) {
                    int row = rt * 16 + quad * 4 + r;
                    sU.p.Acc[w][row][0] = ep[rt][r][0];
                    sU.p.Acc[w][row][1] = ep[rt][r][1];
                    sU.p.Acc[w][row][2] = ep[rt][r][2];
                }
        }
        __syncthreads();

        if (tid < 192) {
            int row = tid / 3, j = tid % 3;
            float v = sU.p.Acc[0][row][j] + sU.p.Acc[1][row][j] + sU.p.Acc[2][row][j] + sU.p.Acc[3][row][j];
            int s = row >> 3, i = row & 7;
            size_t M = m0 + s;
            if (i == 0) { v += pb2[j]; out[M * 18 + j] = v; out[OUTA + M * 6 + j] = v; }
            else        { out[JTOT + M * 63 + j * 7 + (i - 1)] = v;
                          out[JANG + M * 42 + j * 7 + (i - 1)] = v; }
            sU.p.Sum[row][j] = v;
        }
        __syncthreads();
        if (tid < 24) {
            int s = tid / 3, j = tid % 3;
            float vel = 0.f;
            #pragma unroll
            for (int i = 0; i < 7; i++) vel = fmaf(sU.p.Sum[s * 8 + 1 + i][j], sU.p.Qd[s][i], vel);
            out[(size_t)(m0 + s) * 18 + 9 + j] = vel;
        }
    } else {
        // ================= RPY: 7 -> 256 -> 256 -> 2, 16 samples =================
        const int h = r5 - 2;
        const int m0 = g * 16;
        const float* W0 = (h == 0) ? rW0_ : (h == 1) ? piW0 : yW0;
        const float* b0 = (h == 0) ? rb0_ : (h == 1) ? pib0 : yb0;
        const float* b1 = (h == 0) ? rb1_ : (h == 1) ? pib1 : yb1;
        const float* W2 = (h == 0) ? rW2_ : (h == 1) ? piW2 : yW2;
        const float* b2 = (h == 0) ? rb2_ : (h == 1) ? pib2 : yb2;
        const unsigned short* wsW1 = wsBase + 262144 + h * 65536;

        if (tid < 256) { sU.r.B0[tid] = b0[tid]; sU.r.B1[tid] = b1[tid]; }
        for (int i = tid; i < 512; i += 256) sU.r.W2[i] = W2[i];
        if (tid < 224) {
            int m = tid / 14, c = tid % 14;
            float v = x[(m0 + m) * 14 + c];
            if (c < 7) sU.r.Q[m][c] = v; else sU.r.Qd[m][c - 7] = v;
        }
        __syncthreads();

        const float4* W04 = (const float4*)W0;

        floatx4 acc[8][4];
        #pragma unroll
        for (int rt = 0; rt < 8; rt++)
            #pragma unroll
            for (int ct = 0; ct < 4; ct++) acc[rt][ct] = z4;

        const short8* bbase = (const short8*)wsW1 + (size_t)(w * 4 * 8) * 64 + lane;
        short8 bufA[4], bufB[4];

        #pragma unroll
        for (int hh = 0; hh < 2; ++hh) {
            // ---- layer 0, K-half hh: k8 = hh*16 .. hh*16+15, 1 item/thread ----
            {
                const int s = tid >> 4, k8l = tid & 15, k8 = (hh << 4) | k8l;
                float q[7], w0v[7][8];
                #pragma unroll
                for (int i = 0; i < 7; i++) {
                    q[i] = sU.r.Q[s][i];
                    float4 a = W04[i * 64 + k8 * 2], b4 = W04[i * 64 + k8 * 2 + 1];
                    w0v[i][0]=a.x; w0v[i][1]=a.y; w0v[i][2]=a.z; w0v[i][3]=a.w;
                    w0v[i][4]=b4.x; w0v[i][5]=b4.y; w0v[i][6]=b4.z; w0v[i][7]=b4.w;
                }
                float hv[8], dv[8];
                #pragma unroll
                for (int jj = 0; jj < 8; jj++) {
                    float z = sU.r.B0[k8 * 8 + jj];
                    #pragma unroll
                    for (int i = 0; i < 7; i++) z = fmaf(q[i], w0v[i][jj], z);
                    float hhh = sig(z);
                    hv[jj] = hhh; dv[jj] = hhh - hhh * hhh;
                }
                const int ktl = k8l >> 2, kq = k8l & 3;
                const int ktg = (hh << 2) | ktl, sw = ktg;   // sw = (k8>>2)&7
                const int rr0 = s * 8;
                *(short8*)&sA[((rr0 >> 4) * 4 + ktl) * 512 + ((kq * 16 + (rr0 & 15)) ^ sw) * 8]
                    = pack8_bf16(hv);
                #pragma unroll
                for (int i = 0; i < 7; i++) {
                    const int rr = rr0 + 1 + i;
                    float t[8];
                    #pragma unroll
                    for (int jj = 0; jj < 8; jj++) t[jj] = dv[jj] * w0v[i][jj];
                    *(short8*)&sA[((rr >> 4) * 4 + ktl) * 512 + ((kq * 16 + (rr & 15)) ^ sw) * 8]
                        = pack8_bf16(t);
                }
            }
            #pragma unroll
            for (int ct = 0; ct < 4; ++ct) bufA[ct] = bbase[(ct * 8 + hh * 4) * 64];
            __syncthreads();

            for (int kt2 = 0; kt2 < 4; kt2 += 2) {
                #pragma unroll
                for (int ct = 0; ct < 4; ++ct) bufB[ct] = bbase[(ct * 8 + hh * 4 + kt2 + 1) * 64];
                {
                    const int ktl = kt2, sw = (hh << 2) | ktl;
                    short8 afr[8];
                    #pragma unroll
                    for (int rt = 0; rt < 8; ++rt)
                        afr[rt] = *(const short8*)&sA[(rt * 4 + ktl) * 512 + (lane ^ sw) * 8];
                    #pragma unroll
                    for (int ct = 0; ct < 4; ++ct)
                        #pragma unroll
                        for (int rt = 0; rt < 8; ++rt)
                            acc[rt][ct] = __builtin_amdgcn_mfma_f32_16x16x32_bf16(afr[rt], bufA[ct], acc[rt][ct], 0, 0, 0);
                }
                if (kt2 + 2 < 4) {
                    #pragma unroll
                    for (int ct = 0; ct < 4; ++ct) bufA[ct] = bbase[(ct * 8 + hh * 4 + kt2 + 2) * 64];
                }
                {
                    const int ktl = kt2 + 1, sw = (hh << 2) | ktl;
                    short8 afr[8];
                    #pragma unroll
                    for (int rt = 0; rt < 8; ++rt)
                        afr[rt] = *(const short8*)&sA[(rt * 4 + ktl) * 512 + (lane ^ sw) * 8];
                    #pragma unroll
                    for (int ct = 0; ct < 4; ++ct)
                        #pragma unroll
                        for (int rt = 0; rt < 8; ++rt)
                            acc[rt][ct] = __builtin_amdgcn_mfma_f32_16x16x32_bf16(afr[rt], bufB[ct], acc[rt][ct], 0, 0, 0);
                }
            }
            if (hh == 0) __syncthreads();   // drain reads before half-1 overwrites sA
        }

        float ep[8][4][2];
        #pragma unroll
        for (int a = 0; a < 8; a++) for (int b = 0; b < 4; b++) for (int c = 0; c < 2; c++) ep[a][b][c] = 0.f;

        #pragma unroll
        for (int ct = 0; ct < 4; ++ct) {
            const int n = w * 64 + ct * 16 + col;
            const float b1n = sU.r.B1[n];
            const float w20 = sU.r.W2[n * 2], w21 = sU.r.W2[n * 2 + 1];
            #pragma unroll
            for (int rt = 0; rt < 8; ++rt) {
                float z2c = __shfl(acc[rt][ct][0], srcl);
                float h2 = sig(z2c + b1n);
                float d2 = h2 - h2 * h2;
                #pragma unroll
                for (int r = 0; r < 4; ++r) {
                    float gg = ((quad & 1) == 0 && r == 0) ? h2 : d2 * acc[rt][ct][r];
                    ep[rt][r][0] = fmaf(gg, w20, ep[rt][r][0]);
                    ep[rt][r][1] = fmaf(gg, w21, ep[rt][r][1]);
                }
            }
        }

        #pragma unroll
        for (int mask = 1; mask <= 8; mask <<= 1)
            #pragma unroll
            for (int a = 0; a < 8; a++)
                #pragma unroll
                for (int b = 0; b < 4; b++)
                    #pragma unroll
                    for (int c = 0; c < 2; c++)
                        ep[a][b][c] += __shfl_xor(ep[a][b][c], mask);
        if (col == 0) {
            #pragma unroll
            for (int rt = 0; rt < 8; ++rt)
                #pragma unroll
                for (int r = 0; r < 4; ++r) {
                    int row = rt * 16 + quad * 4 + r;
                    sU.r.Acc[w][row][0] = ep[rt][r][0];
                    sU.r.Acc[w][row][1] = ep[rt][r][1];
                }
        }
        __syncthreads();

        if (tid < 256) {
            int row = tid >> 1, j = tid & 1;
            float v = sU.r.Acc[0][row][j] + sU.r.Acc[1][row][j] + sU.r.Acc[2][row][j] + sU.r.Acc[3][row][j];
            if ((row & 7) == 0) v += b2[j];
            sU.r.Sum[row][j] = v;
        }
        __syncthreads();

        if (tid < 16) {
            int s = tid;
            size_t M = m0 + s;
            float y0 = sU.r.Sum[s * 8][0], y1 = sU.r.Sum[s * 8][1];
            float sv = sinf(y0), cv = cosf(y1);
            out[M * 18 + 3 + h] = sv;
            out[M * 18 + 6 + h] = cv;
            out[OUTA + M * 6 + 3 + h] = atan2f(sv, cv);
            float f0 = cosf(y0), f1 = -sinf(y1);
            float inv = 1.0f / fmaf(sv, sv, cv * cv);
            float v0 = 0.f, v1 = 0.f;
            #pragma unroll
            for (int i = 0; i < 7; i++) {
                float r0 = f0 * sU.r.Sum[s * 8 + 1 + i][0];
                float r1 = f1 * sU.r.Sum[s * 8 + 1 + i][1];
                out[JTOT + M * 63 + (3 + h) * 7 + i] = r0;
                out[JTOT + M * 63 + (6 + h) * 7 + i] = r1;
                out[JANG + M * 42 + (3 + h) * 7 + i] = (cv * r0 - sv * r1) * inv;
                v0 = fmaf(r0, sU.r.Qd[s][i], v0);
                v1 = fmaf(r1, sU.r.Qd[s][i], v1);
            }
            out[M * 18 + 12 + h] = v0;
            out[M * 18 + 15 + h] = v1;
        }
    }
}

extern "C" void kernel_launch(void* const* d_in, const int* in_sizes, int n_in,
                              void* d_out, int out_size, void* d_ws, size_t ws_size,
                              hipStream_t stream) {
    (void)n_in; (void)out_size; (void)ws_size;
    const float* x = (const float*)d_in[0];
    float* out = (float*)d_out;
    unsigned short* ws = (unsigned short*)d_ws;
    const int ns = in_sizes[0] / 14;

    convert_all<<<dim3(1792), 256, 0, stream>>>(
        (const float*)d_in[3], (const float*)d_in[9],
        (const float*)d_in[15], (const float*)d_in[21], ws);

    // 5120 blocks; XCD-colocated remap done inside the kernel; 32KB dynamic LDS
    fused_mfma<<<dim3((ns / 8 / 2) * 5), 256, 32768, stream>>>(
        x,
        (const float*)d_in[1],  (const float*)d_in[2],  (const float*)d_in[4],
        (const float*)d_in[5],  (const float*)d_in[6],
        (const float*)d_in[7],  (const float*)d_in[8],  (const float*)d_in[10],
        (const float*)d_in[11], (const float*)d_in[12],
        (const float*)d_in[13], (const float*)d_in[14], (const float*)d_in[16],
        (const float*)d_in[17], (const float*)d_in[18],
        (const float*)d_in[19], (const float*)d_in[20], (const float*)d_in[22],
        (const float*)d_in[23], (const float*)d_in[24],
        ws, out, ns);
}

// Round 3
// 321.073 us; speedup vs baseline: 2.5002x; 2.5002x over previous
//
#include <hip/hip_runtime.h>
#include <math.h>

typedef __attribute__((ext_vector_type(8))) short short8;
typedef __attribute__((ext_vector_type(4))) float floatx4;

__device__ __forceinline__ float sig(float z) { return 1.0f / (1.0f + __expf(-z)); }

__device__ __forceinline__ unsigned short f2bf(float f) {
    unsigned u = __float_as_uint(f);
    u = (u + 0x7FFFu + ((u >> 16) & 1u)) >> 16;   // RNE
    return (unsigned short)u;
}

// v_cvt_pk_bf16_f32: packs 2 f32 -> 2 bf16 (RNE) in one instruction.
__device__ __forceinline__ unsigned cvtpk_bf16(float lo, float hi) {
    unsigned r;
    asm("v_cvt_pk_bf16_f32 %0, %1, %2" : "=v"(r) : "v"(lo), "v"(hi));
    return r;
}

__device__ __forceinline__ short8 pack8_bf16(const float* v) {
    union { short8 s; unsigned u[4]; } r;
    r.u[0] = cvtpk_bf16(v[0], v[1]);
    r.u[1] = cvtpk_bf16(v[2], v[3]);
    r.u[2] = cvtpk_bf16(v[4], v[5]);
    r.u[3] = cvtpk_bf16(v[6], v[7]);
    return r.s;
}

// All four W1 matrices -> bf16 pre-swizzled MFMA 16x16x32 B-frag order.
// blk = (n>>4)*(H/32) + (k>>5), lane = ((k>>3)&3)*16 + (n&15), j = k&7.
__global__ void convert_all(const float* __restrict__ s0, const float* __restrict__ s1,
                            const float* __restrict__ s2, const float* __restrict__ s3,
                            unsigned short* __restrict__ ws) {
    int idx = blockIdx.x * 256 + threadIdx.x;          // 0 .. 458751
    const float* src; unsigned short* dst; int H, logH, local;
    if (idx < 262144) { src = s0; dst = ws; H = 512; logH = 9; local = idx; }
    else {
        int r = idx - 262144; int m = r >> 16; local = r & 65535;
        H = 256; logH = 8;
        src = (m == 0) ? s1 : (m == 1) ? s2 : s3;
        dst = ws + 262144 + m * 65536;
    }
    int n = local & (H - 1), k = local >> logH;
    int KT = H >> 5;
    int blk = (n >> 4) * KT + (k >> 5);
    int lane = ((k >> 3) & 3) * 16 + (n & 15);
    int j = k & 7;
    dst[(blk * 64 + lane) * 8 + j] = f2bf(src[local]);
}

// R3: halved per-block sample tiles (pos 4 samples, rpy 8) so the accumulator
// is 64 regs (was 128); B-loads done in 2 ct-passes per K-half (buf regs 32,
// was 64); K-split A-tile 16KB dynamic LDS. Total regs ~150-160 -> fits the
// 170-reg budget of launch_bounds(256,3): 3 blocks/CU (R2 spill post-mortem:
// (256,3) on the 256-reg body spilled acc to scratch, FETCH 8MB->1.16GB).
// Grid 10240: octet o of 8 samples -> 5 blocks (2 pos x 4s, 3 rpy x 8s),
// XCD-colocated (o%8) so co-writers of an output line share one L2.
struct PosS {
    float B0[512], B1[512], W2[1536];
    float Q[4][8], Qd[4][8];
    float Acc[4][32][3], Sum[32][3];
};
struct RpyS {
    float B0[256], B1[256], W2[512];
    float Q[8][8], Qd[8][8];
    float Acc[4][64][2], Sum[64][2];
};

__global__ __launch_bounds__(256, 3)
void fused_mfma(const float* __restrict__ x,
                const float* __restrict__ pW0, const float* __restrict__ pb0,
                const float* __restrict__ pb1,
                const float* __restrict__ pW2, const float* __restrict__ pb2,
                const float* __restrict__ rW0_, const float* __restrict__ rb0_,
                const float* __restrict__ rb1_,
                const float* __restrict__ rW2_, const float* __restrict__ rb2_,
                const float* __restrict__ piW0, const float* __restrict__ pib0,
                const float* __restrict__ pib1,
                const float* __restrict__ piW2, const float* __restrict__ pib2,
                const float* __restrict__ yW0, const float* __restrict__ yb0,
                const float* __restrict__ yb1,
                const float* __restrict__ yW2, const float* __restrict__ yb2,
                const unsigned short* __restrict__ wsBase,
                float* __restrict__ out, int ns)
{
    extern __shared__ unsigned short sA[];      // 16 KB dynamic (one K-half)
    __shared__ union { PosS p; RpyS r; } sU;

    const int tid = threadIdx.x;
    const int xcd  = blockIdx.x & 7;
    const int slot = blockIdx.x >> 3;           // 0..1279 within this XCD
    const int o_l  = slot / 5, r5 = slot % 5;
    const int o = xcd + (o_l << 3);             // sample-octet 0..2047

    const size_t JTOT = (size_t)ns * 18, OUTA = (size_t)ns * 81, JANG = (size_t)ns * 87;
    const floatx4 z4 = {0.f, 0.f, 0.f, 0.f};
    const int w = tid >> 6, lane = tid & 63;
    const int quad = lane >> 4, col = lane & 15;
    const int srcl = lane & 47;

    if (r5 < 2) {
        // ============ POS: 7 -> 512 -> 512 -> 3, 4 samples (32 rows) ============
        const int m0 = (o * 2 + r5) * 4;
        const unsigned short* wsW1 = wsBase;

        for (int i = tid; i < 512;  i += 256) { sU.p.B0[i] = pb0[i]; sU.p.B1[i] = pb1[i]; }
        for (int i = tid; i < 1536; i += 256) sU.p.W2[i] = pW2[i];
        if (tid < 56) {
            int m = tid / 14, c = tid % 14;
            float v = x[(m0 + m) * 14 + c];
            if (c < 7) sU.p.Q[m][c] = v; else sU.p.Qd[m][c - 7] = v;
        }
        __syncthreads();

        const float4* W04 = (const float4*)pW0;

        floatx4 acc[2][8];
        #pragma unroll
        for (int rt = 0; rt < 2; rt++)
            #pragma unroll
            for (int ct = 0; ct < 8; ct++) acc[rt][ct] = z4;

        const short8* bbase = (const short8*)wsW1 + (size_t)(w * 8 * 16) * 64 + lane;
        short8 bufA[4], bufB[4];

        #pragma unroll
        for (int hh = 0; hh < 2; ++hh) {
            // ---- layer 0, K-half hh: 128 items (4 samples x 32 k8) ----
            if (tid < 128) {
                const int s = tid >> 5, k8l = tid & 31, k8 = (hh << 5) | k8l;
                float q[7], w0v[7][8];
                #pragma unroll
                for (int i = 0; i < 7; i++) {
                    q[i] = sU.p.Q[s][i];
                    float4 a = W04[i * 128 + k8 * 2], b4 = W04[i * 128 + k8 * 2 + 1];
                    w0v[i][0]=a.x; w0v[i][1]=a.y; w0v[i][2]=a.z; w0v[i][3]=a.w;
                    w0v[i][4]=b4.x; w0v[i][5]=b4.y; w0v[i][6]=b4.z; w0v[i][7]=b4.w;
                }
                float hv[8], dv[8];
                #pragma unroll
                for (int jj = 0; jj < 8; jj++) {
                    float z = sU.p.B0[k8 * 8 + jj];
                    #pragma unroll
                    for (int i = 0; i < 7; i++) z = fmaf(q[i], w0v[i][jj], z);
                    float h = sig(z);
                    hv[jj] = h; dv[jj] = h - h * h;
                }
                const int ktl = k8l >> 2, kq = k8l & 3, sw = ktl; // sw = (k8>>2)&7
                const int rr0 = s * 8;
                *(short8*)&sA[((rr0 >> 4) * 8 + ktl) * 512 + ((kq * 16 + (rr0 & 15)) ^ sw) * 8]
                    = pack8_bf16(hv);
                #pragma unroll
                for (int i = 0; i < 7; i++) {
                    const int rr = rr0 + 1 + i;
                    float t[8];
                    #pragma unroll
                    for (int jj = 0; jj < 8; jj++) t[jj] = dv[jj] * w0v[i][jj];
                    *(short8*)&sA[((rr >> 4) * 8 + ktl) * 512 + ((kq * 16 + (rr & 15)) ^ sw) * 8]
                        = pack8_bf16(t);
                }
            }
            __syncthreads();

            // ---- layer 1 MFMA over this K-half, 2 ct-passes of 4 ----
            #pragma unroll
            for (int cp = 0; cp < 2; ++cp) {
                #pragma unroll
                for (int c = 0; c < 4; ++c)
                    bufA[c] = bbase[((cp * 4 + c) * 16 + hh * 8) * 64];
                for (int kt2 = 0; kt2 < 8; kt2 += 2) {
                    #pragma unroll
                    for (int c = 0; c < 4; ++c)
                        bufB[c] = bbase[((cp * 4 + c) * 16 + hh * 8 + kt2 + 1) * 64];
                    {
                        const int ktl = kt2, sw = ktl;
                        short8 afr[2];
                        #pragma unroll
                        for (int rt = 0; rt < 2; ++rt)
                            afr[rt] = *(const short8*)&sA[(rt * 8 + ktl) * 512 + (lane ^ sw) * 8];
                        #pragma unroll
                        for (int c = 0; c < 4; ++c)
                            #pragma unroll
                            for (int rt = 0; rt < 2; ++rt)
                                acc[rt][cp * 4 + c] = __builtin_amdgcn_mfma_f32_16x16x32_bf16(afr[rt], bufA[c], acc[rt][cp * 4 + c], 0, 0, 0);
                    }
                    if (kt2 + 2 < 8) {
                        #pragma unroll
                        for (int c = 0; c < 4; ++c)
                            bufA[c] = bbase[((cp * 4 + c) * 16 + hh * 8 + kt2 + 2) * 64];
                    }
                    {
                        const int ktl = kt2 + 1, sw = ktl;
                        short8 afr[2];
                        #pragma unroll
                        for (int rt = 0; rt < 2; ++rt)
                            afr[rt] = *(const short8*)&sA[(rt * 8 + ktl) * 512 + (lane ^ sw) * 8];
                        #pragma unroll
                        for (int c = 0; c < 4; ++c)
                            #pragma unroll
                            for (int rt = 0; rt < 2; ++rt)
                                acc[rt][cp * 4 + c] = __builtin_amdgcn_mfma_f32_16x16x32_bf16(afr[rt], bufB[c], acc[rt][cp * 4 + c], 0, 0, 0);
                    }
                }
            }
            if (hh == 0) __syncthreads();   // drain reads before half-1 overwrites sA
        }

        float ep[2][4][3];
        #pragma unroll
        for (int a = 0; a < 2; a++) for (int b = 0; b < 4; b++) for (int c = 0; c < 3; c++) ep[a][b][c] = 0.f;

        #pragma unroll
        for (int ct = 0; ct < 8; ++ct) {
            const int n = w * 128 + ct * 16 + col;
            const float b1n = sU.p.B1[n];
            const float w20 = sU.p.W2[n * 3], w21 = sU.p.W2[n * 3 + 1], w22 = sU.p.W2[n * 3 + 2];
            #pragma unroll
            for (int rt = 0; rt < 2; ++rt) {
                float z2c = __shfl(acc[rt][ct][0], srcl);
                float h2 = sig(z2c + b1n);
                float d2 = h2 - h2 * h2;
                #pragma unroll
                for (int r = 0; r < 4; ++r) {
                    float gg = ((quad & 1) == 0 && r == 0) ? h2 : d2 * acc[rt][ct][r];
                    ep[rt][r][0] = fmaf(gg, w20, ep[rt][r][0]);
                    ep[rt][r][1] = fmaf(gg, w21, ep[rt][r][1]);
                    ep[rt][r][2] = fmaf(gg, w22, ep[rt][r][2]);
                }
            }
        }

        #pragma unroll
        for (int mask = 1; mask <= 8; mask <<= 1)
            #pragma unroll
            for (int a = 0; a < 2; a++)
                #pragma unroll
                for (int b = 0; b < 4; b++)
                    #pragma unroll
                    for (int c = 0; c < 3; c++)
                        ep[a][b][c] += __shfl_xor(ep[a][b][c], mask);
        if (col == 0) {
            #pragma unroll
            for (int rt = 0; rt < 2; ++rt)
                #pragma unroll
                for (int r = 0; r < 4; ++r) {
                    int row = rt * 16 + quad * 4 + r;
                    sU.p.Acc[w][row][0] = ep[rt][r][0];
                    sU.p.Acc[w][row][1] = ep[rt][r][1];
                    sU.p.Acc[w][row][2] = ep[rt][r][2];
                }
        }
        __syncthreads();

        if (tid < 96) {
            int row = tid / 3, j = tid % 3;
            float v = sU.p.Acc[0][row][j] + sU.p.Acc[1][row][j] + sU.p.Acc[2][row][j] + sU.p.Acc[3][row][j];
            int s = row >> 3, i = row & 7;
            size_t M = m0 + s;
            if (i == 0) { v += pb2[j]; out[M * 18 + j] = v; out[OUTA + M * 6 + j] = v; }
            else        { out[JTOT + M * 63 + j * 7 + (i - 1)] = v;
                          out[JANG + M * 42 + j * 7 + (i - 1)] = v; }
            sU.p.Sum[row][j] = v;
        }
        __syncthreads();
        if (tid < 12) {
            int s = tid / 3, j = tid % 3;
            float vel = 0.f;
            #pragma unroll
            for (int i = 0; i < 7; i++) vel = fmaf(sU.p.Sum[s * 8 + 1 + i][j], sU.p.Qd[s][i], vel);
            out[(size_t)(m0 + s) * 18 + 9 + j] = vel;
        }
    } else {
        // ============ RPY: 7 -> 256 -> 256 -> 2, 8 samples (64 rows) ============
        const int h = r5 - 2;
        const int m0 = o * 8;
        const float* W0 = (h == 0) ? rW0_ : (h == 1) ? piW0 : yW0;
        const float* b0 = (h == 0) ? rb0_ : (h == 1) ? pib0 : yb0;
        const float* b1 = (h == 0) ? rb1_ : (h == 1) ? pib1 : yb1;
        const float* W2 = (h == 0) ? rW2_ : (h == 1) ? piW2 : yW2;
        const float* b2 = (h == 0) ? rb2_ : (h == 1) ? pib2 : yb2;
        const unsigned short* wsW1 = wsBase + 262144 + h * 65536;

        if (tid < 256) { sU.r.B0[tid] = b0[tid]; sU.r.B1[tid] = b1[tid]; }
        for (int i = tid; i < 512; i += 256) sU.r.W2[i] = W2[i];
        if (tid < 112) {
            int m = tid / 14, c = tid % 14;
            float v = x[(m0 + m) * 14 + c];
            if (c < 7) sU.r.Q[m][c] = v; else sU.r.Qd[m][c - 7] = v;
        }
        __syncthreads();

        const float4* W04 = (const float4*)W0;

        floatx4 acc[4][4];
        #pragma unroll
        for (int rt = 0; rt < 4; rt++)
            #pragma unroll
            for (int ct = 0; ct < 4; ct++) acc[rt][ct] = z4;

        const short8* bbase = (const short8*)wsW1 + (size_t)(w * 4 * 8) * 64 + lane;
        short8 bufA[2], bufB[2];

        #pragma unroll
        for (int hh = 0; hh < 2; ++hh) {
            // ---- layer 0, K-half hh: 128 items (8 samples x 16 k8) ----
            if (tid < 128) {
                const int s = tid >> 4, k8l = tid & 15, k8 = (hh << 4) | k8l;
                float q[7], w0v[7][8];
                #pragma unroll
                for (int i = 0; i < 7; i++) {
                    q[i] = sU.r.Q[s][i];
                    float4 a = W04[i * 64 + k8 * 2], b4 = W04[i * 64 + k8 * 2 + 1];
                    w0v[i][0]=a.x; w0v[i][1]=a.y; w0v[i][2]=a.z; w0v[i][3]=a.w;
                    w0v[i][4]=b4.x; w0v[i][5]=b4.y; w0v[i][6]=b4.z; w0v[i][7]=b4.w;
                }
                float hv[8], dv[8];
                #pragma unroll
                for (int jj = 0; jj < 8; jj++) {
                    float z = sU.r.B0[k8 * 8 + jj];
                    #pragma unroll
                    for (int i = 0; i < 7; i++) z = fmaf(q[i], w0v[i][jj], z);
                    float hhh = sig(z);
                    hv[jj] = hhh; dv[jj] = hhh - hhh * hhh;
                }
                const int ktl = k8l >> 2, kq = k8l & 3;
                const int sw = (hh << 2) | ktl;              // global kt & 7
                const int rr0 = s * 8;
                *(short8*)&sA[((rr0 >> 4) * 4 + ktl) * 512 + ((kq * 16 + (rr0 & 15)) ^ sw) * 8]
                    = pack8_bf16(hv);
                #pragma unroll
                for (int i = 0; i < 7; i++) {
                    const int rr = rr0 + 1 + i;
                    float t[8];
                    #pragma unroll
                    for (int jj = 0; jj < 8; jj++) t[jj] = dv[jj] * w0v[i][jj];
                    *(short8*)&sA[((rr >> 4) * 4 + ktl) * 512 + ((kq * 16 + (rr & 15)) ^ sw) * 8]
                        = pack8_bf16(t);
                }
            }
            __syncthreads();

            // ---- layer 1 MFMA over this K-half, 2 ct-passes of 2 ----
            #pragma unroll
            for (int cp = 0; cp < 2; ++cp) {
                #pragma unroll
                for (int c = 0; c < 2; ++c)
                    bufA[c] = bbase[((cp * 2 + c) * 8 + hh * 4) * 64];
                for (int kt2 = 0; kt2 < 4; kt2 += 2) {
                    #pragma unroll
                    for (int c = 0; c < 2; ++c)
                        bufB[c] = bbase[((cp * 2 + c) * 8 + hh * 4 + kt2 + 1) * 64];
                    {
                        const int ktl = kt2, sw = (hh << 2) | ktl;
                        short8 afr[4];
                        #pragma unroll
                        for (int rt = 0; rt < 4; ++rt)
                            afr[rt] = *(const short8*)&sA[(rt * 4 + ktl) * 512 + (lane ^ sw) * 8];
                        #pragma unroll
                        for (int c = 0; c < 2; ++c)
                            #pragma unroll
                            for (int rt = 0; rt < 4; ++rt)
                                acc[rt][cp * 2 + c] = __builtin_amdgcn_mfma_f32_16x16x32_bf16(afr[rt], bufA[c], acc[rt][cp * 2 + c], 0, 0, 0);
                    }
                    if (kt2 + 2 < 4) {
                        #pragma unroll
                        for (int c = 0; c < 2; ++c)
                            bufA[c] = bbase[((cp * 2 + c) * 8 + hh * 4 + kt2 + 2) * 64];
                    }
                    {
                        const int ktl = kt2 + 1, sw = (hh << 2) | ktl;
                        short8 afr[4];
                        #pragma unroll
                        for (int rt = 0; rt < 4; ++rt)
                            afr[rt] = *(const short8*)&sA[(rt * 4 + ktl) * 512 + (lane ^ sw) * 8];
                        #pragma unroll
                        for (int c = 0; c < 2; ++c)
                            #pragma unroll
                            for (int rt = 0; rt < 4; ++rt)
                                acc[rt][cp * 2 + c] = __builtin_amdgcn_mfma_f32_16x16x32_bf16(afr[rt], bufB[c], acc[rt][cp * 2 + c], 0, 0, 0);
                    }
                }
            }
            if (hh == 0) __syncthreads();   // drain reads before half-1 overwrites sA
        }

        float ep[4][4][2];
        #pragma unroll
        for (int a = 0; a < 4; a++) for (int b = 0; b < 4; b++) for (int c = 0; c < 2; c++) ep[a][b][c] = 0.f;

        #pragma unroll
        for (int ct = 0; ct < 4; ++ct) {
            const int n = w * 64 + ct * 16 + col;
            const float b1n = sU.r.B1[n];
            const float w20 = sU.r.W2[n * 2], w21 = sU.r.W2[n * 2 + 1];
            #pragma unroll
            for (int rt = 0; rt < 4; ++rt) {
                float z2c = __shfl(acc[rt][ct][0], srcl);
                float h2 = sig(z2c + b1n);
                float d2 = h2 - h2 * h2;
                #pragma unroll
                for (int r = 0; r < 4; ++r) {
                    float gg = ((quad & 1) == 0 && r == 0) ? h2 : d2 * acc[rt][ct][r];
                    ep[rt][r][0] = fmaf(gg, w20, ep[rt][r][0]);
                    ep[rt][r][1] = fmaf(gg, w21, ep[rt][r][1]);
                }
            }
        }

        #pragma unroll
        for (int mask = 1; mask <= 8; mask <<= 1)
            #pragma unroll
            for (int a = 0; a < 4; a++)
                #pragma unroll
                for (int b = 0; b < 4; b++)
                    #pragma unroll
                    for (int c = 0; c < 2; c++)
                        ep[a][b][c] += __shfl_xor(ep[a][b][c], mask);
        if (col == 0) {
            #pragma unroll
            for (int rt = 0; rt < 4; ++rt)
                #pragma unroll
                for (int r = 0; r < 4; ++r) {
                    int row = rt * 16 + quad * 4 + r;
                    sU.r.Acc[w][row][0] = ep[rt][r][0];
                    sU.r.Acc[w][row][1] = ep[rt][r][1];
                }
        }
        __syncthreads();

        if (tid < 128) {
            int row = tid >> 1, j = tid & 1;
            float v = sU.r.Acc[0][row][j] + sU.r.Acc[1][row][j] + sU.r.Acc[2][row][j] + sU.r.Acc[3][row][j];
            if ((row & 7) == 0) v += b2[j];
            sU.r.Sum[row][j] = v;
        }
        __syncthreads();

        if (tid < 8) {
            int s = tid;
            size_t M = m0 + s;
            float y0 = sU.r.Sum[s * 8][0], y1 = sU.r.Sum[s * 8][1];
            float sv = sinf(y0), cv = cosf(y1);
            out[M * 18 + 3 + h] = sv;
            out[M * 18 + 6 + h] = cv;
            out[OUTA + M * 6 + 3 + h] = atan2f(sv, cv);
            float f0 = cosf(y0), f1 = -sinf(y1);
            float inv = 1.0f / fmaf(sv, sv, cv * cv);
            float v0 = 0.f, v1 = 0.f;
            #pragma unroll
            for (int i = 0; i < 7; i++) {
                float r0 = f0 * sU.r.Sum[s * 8 + 1 + i][0];
                float r1 = f1 * sU.r.Sum[s * 8 + 1 + i][1];
                out[JTOT + M * 63 + (3 + h) * 7 + i] = r0;
                out[JTOT + M * 63 + (6 + h) * 7 + i] = r1;
                out[JANG + M * 42 + (3 + h) * 7 + i] = (cv * r0 - sv * r1) * inv;
                v0 = fmaf(r0, sU.r.Qd[s][i], v0);
                v1 = fmaf(r1, sU.r.Qd[s][i], v1);
            }
            out[M * 18 + 12 + h] = v0;
            out[M * 18 + 15 + h] = v1;
        }
    }
}

extern "C" void kernel_launch(void* const* d_in, const int* in_sizes, int n_in,
                              void* d_out, int out_size, void* d_ws, size_t ws_size,
                              hipStream_t stream) {
    (void)n_in; (void)out_size; (void)ws_size;
    const float* x = (const float*)d_in[0];
    float* out = (float*)d_out;
    unsigned short* ws = (unsigned short*)d_ws;
    const int ns = in_sizes[0] / 14;

    convert_all<<<dim3(1792), 256, 0, stream>>>(
        (const float*)d_in[3], (const float*)d_in[9],
        (const float*)d_in[15], (const float*)d_in[21], ws);

    // 10240 blocks (2048 octets x 5 roles); 16KB dynamic LDS
    fused_mfma<<<dim3((ns / 8) * 5), 256, 16384, stream>>>(
        x,
        (const float*)d_in[1],  (const float*)d_in[2],  (const float*)d_in[4],
        (const float*)d_in[5],  (const float*)d_in[6],
        (const float*)d_in[7],  (const float*)d_in[8],  (const float*)d_in[10],
        (const float*)d_in[11], (const float*)d_in[12],
        (const float*)d_in[13], (const float*)d_in[14], (const float*)d_in[16],
        (const float*)d_in[17], (const float*)d_in[18],
        (const float*)d_in[19], (const float*)d_in[20], (const float*)d_in[22],
        (const float*)d_in[23], (const float*)d_in[24],
        ws, out, ns);
}

// Round 4
// 307.145 us; speedup vs baseline: 2.6136x; 1.0453x over previous
//
#include <hip/hip_runtime.h>
#include <math.h>

typedef __attribute__((ext_vector_type(8))) short short8;
typedef __attribute__((ext_vector_type(4))) float floatx4;
typedef __attribute__((ext_vector_type(2))) unsigned uint2v;

__device__ __forceinline__ float sig(float z) { return 1.0f / (1.0f + __expf(-z)); }

__device__ __forceinline__ unsigned short f2bf(float f) {
    unsigned u = __float_as_uint(f);
    u = (u + 0x7FFFu + ((u >> 16) & 1u)) >> 16;   // RNE
    return (unsigned short)u;
}

// v_cvt_pk_bf16_f32: packs 2 f32 -> 2 bf16 (RNE) in one instruction.
__device__ __forceinline__ unsigned cvtpk_bf16(float lo, float hi) {
    unsigned r;
    asm("v_cvt_pk_bf16_f32 %0, %1, %2" : "=v"(r) : "v"(lo), "v"(hi));
    return r;
}

// 4 floats -> 4 bf16 (8B store), RNE identical to f2bf.
__device__ __forceinline__ void st_pack4(unsigned short* p, float v0, float v1, float v2, float v3) {
    uint2v u;
    u.x = cvtpk_bf16(v0, v1);
    u.y = cvtpk_bf16(v2, v3);
    *(uint2v*)p = u;
}

// All four W1 matrices -> bf16 pre-swizzled MFMA 16x16x32 B-frag order.
// blk = (n>>4)*(H/32) + (k>>5), lane = ((k>>3)&3)*16 + (n&15), j = k&7.
__global__ void convert_all(const float* __restrict__ s0, const float* __restrict__ s1,
                            const float* __restrict__ s2, const float* __restrict__ s3,
                            unsigned short* __restrict__ ws) {
    int idx = blockIdx.x * 256 + threadIdx.x;          // 0 .. 458751
    const float* src; unsigned short* dst; int H, logH, local;
    if (idx < 262144) { src = s0; dst = ws; H = 512; logH = 9; local = idx; }
    else {
        int r = idx - 262144; int m = r >> 16; local = r & 65535;
        H = 256; logH = 8;
        src = (m == 0) ? s1 : (m == 1) ? s2 : s3;
        dst = ws + 262144 + m * 65536;
    }
    int n = local & (H - 1), k = local >> logH;
    int KT = H >> 5;
    int blk = (n >> 4) * KT + (k >> 5);
    int lane = ((k >> 3) & 3) * 16 + (n & 15);
    int j = k & 7;
    dst[(blk * 64 + lane) * 8 + j] = f2bf(src[local]);
}

// R4 (on R3's 251.9us base; R3 post-mortem: occupancy 20->31% but dur -3% ->
// phases latency-bound, not co-residency-bound):
//  - 3-buffer B-frag rotation (load kt+3 while computing kt): prefetch distance
//    ~190cy ~ L2 hit latency, was ~90-140cy (vmcnt stall every half-step).
//  - layer0 now uses all 256 threads (jj-halves split across thread pairs;
//    same per-chain fma order -> bit-identical).
//  - s_setprio(1) around MFMA clusters (3 blocks/CU at skewed phases = role
//    diversity, T5 precondition).
// Regs: ~100 VGPR + 64 AGPR < 170 budget of launch_bounds(256,3). Spill
// sentinel: FETCH_SIZE must stay ~11MB (R2 spill showed 1.16GB).
struct PosS {
    float B0[512], B1[512], W2[1536];
    float Q[4][8], Qd[4][8];
    float Acc[4][32][3], Sum[32][3];
};
struct RpyS {
    float B0[256], B1[256], W2[512];
    float Q[8][8], Qd[8][8];
    float Acc[4][64][2], Sum[64][2];
};

__global__ __launch_bounds__(256, 3)
void fused_mfma(const float* __restrict__ x,
                const float* __restrict__ pW0, const float* __restrict__ pb0,
                const float* __restrict__ pb1,
                const float* __restrict__ pW2, const float* __restrict__ pb2,
                const float* __restrict__ rW0_, const float* __restrict__ rb0_,
                const float* __restrict__ rb1_,
                const float* __restrict__ rW2_, const float* __restrict__ rb2_,
                const float* __restrict__ piW0, const float* __restrict__ pib0,
                const float* __restrict__ pib1,
                const float* __restrict__ piW2, const float* __restrict__ pib2,
                const float* __restrict__ yW0, const float* __restrict__ yb0,
                const float* __restrict__ yb1,
                const float* __restrict__ yW2, const float* __restrict__ yb2,
                const unsigned short* __restrict__ wsBase,
                float* __restrict__ out, int ns)
{
    extern __shared__ unsigned short sA[];      // 16 KB dynamic (one K-half)
    __shared__ union { PosS p; RpyS r; } sU;

    const int tid = threadIdx.x;
    const int xcd  = blockIdx.x & 7;
    const int slot = blockIdx.x >> 3;           // 0..1279 within this XCD
    const int o_l  = slot / 5, r5 = slot % 5;
    const int o = xcd + (o_l << 3);             // sample-octet 0..2047

    const size_t JTOT = (size_t)ns * 18, OUTA = (size_t)ns * 81, JANG = (size_t)ns * 87;
    const floatx4 z4 = {0.f, 0.f, 0.f, 0.f};
    const int w = tid >> 6, lane = tid & 63;
    const int quad = lane >> 4, col = lane & 15;
    const int srcl = lane & 47;

    if (r5 < 2) {
        // ============ POS: 7 -> 512 -> 512 -> 3, 4 samples (32 rows) ============
        const int m0 = (o * 2 + r5) * 4;
        const unsigned short* wsW1 = wsBase;

        for (int i = tid; i < 512;  i += 256) { sU.p.B0[i] = pb0[i]; sU.p.B1[i] = pb1[i]; }
        for (int i = tid; i < 1536; i += 256) sU.p.W2[i] = pW2[i];
        if (tid < 56) {
            int m = tid / 14, c = tid % 14;
            float v = x[(m0 + m) * 14 + c];
            if (c < 7) sU.p.Q[m][c] = v; else sU.p.Qd[m][c - 7] = v;
        }
        __syncthreads();

        const float4* W04 = (const float4*)pW0;

        floatx4 acc[2][8];
        #pragma unroll
        for (int rt = 0; rt < 2; rt++)
            #pragma unroll
            for (int ct = 0; ct < 8; ct++) acc[rt][ct] = z4;

        const short8* bbase = (const short8*)wsW1 + (size_t)(w * 8 * 16) * 64 + lane;
        short8 b0[4], b1[4], b2[4];

#define PLD(B, KT) { \
            B[0] = bbase[((cp4 + 0) * 16 + hh8 + (KT)) * 64]; \
            B[1] = bbase[((cp4 + 1) * 16 + hh8 + (KT)) * 64]; \
            B[2] = bbase[((cp4 + 2) * 16 + hh8 + (KT)) * 64]; \
            B[3] = bbase[((cp4 + 3) * 16 + hh8 + (KT)) * 64]; }
#define PST(B, KT) { \
            const short8 a0 = *(const short8*)&sA[(0 * 8 + (KT)) * 512 + (lane ^ (KT)) * 8]; \
            const short8 a1 = *(const short8*)&sA[(1 * 8 + (KT)) * 512 + (lane ^ (KT)) * 8]; \
            acc[0][cp4 + 0] = __builtin_amdgcn_mfma_f32_16x16x32_bf16(a0, B[0], acc[0][cp4 + 0], 0, 0, 0); \
            acc[1][cp4 + 0] = __builtin_amdgcn_mfma_f32_16x16x32_bf16(a1, B[0], acc[1][cp4 + 0], 0, 0, 0); \
            acc[0][cp4 + 1] = __builtin_amdgcn_mfma_f32_16x16x32_bf16(a0, B[1], acc[0][cp4 + 1], 0, 0, 0); \
            acc[1][cp4 + 1] = __builtin_amdgcn_mfma_f32_16x16x32_bf16(a1, B[1], acc[1][cp4 + 1], 0, 0, 0); \
            acc[0][cp4 + 2] = __builtin_amdgcn_mfma_f32_16x16x32_bf16(a0, B[2], acc[0][cp4 + 2], 0, 0, 0); \
            acc[1][cp4 + 2] = __builtin_amdgcn_mfma_f32_16x16x32_bf16(a1, B[2], acc[1][cp4 + 2], 0, 0, 0); \
            acc[0][cp4 + 3] = __builtin_amdgcn_mfma_f32_16x16x32_bf16(a0, B[3], acc[0][cp4 + 3], 0, 0, 0); \
            acc[1][cp4 + 3] = __builtin_amdgcn_mfma_f32_16x16x32_bf16(a1, B[3], acc[1][cp4 + 3], 0, 0, 0); }

        #pragma unroll
        for (int hh = 0; hh < 2; ++hh) {
            const int hh8 = hh * 8;
            // ---- layer 0, K-half hh: 256 threads = 4 samples x 32 k8 x 2 jj-halves ----
            {
                const int jh = tid & 1, item = tid >> 1;
                const int s = item >> 5, k8l = item & 31, k8 = (hh << 5) | k8l;
                float q[7], w0v[7][4];
                #pragma unroll
                for (int i = 0; i < 7; i++) {
                    q[i] = sU.p.Q[s][i];
                    float4 a = W04[i * 128 + k8 * 2 + jh];
                    w0v[i][0] = a.x; w0v[i][1] = a.y; w0v[i][2] = a.z; w0v[i][3] = a.w;
                }
                float hv[4], dv[4];
                #pragma unroll
                for (int jj = 0; jj < 4; jj++) {
                    float z = sU.p.B0[k8 * 8 + jh * 4 + jj];
                    #pragma unroll
                    for (int i = 0; i < 7; i++) z = fmaf(q[i], w0v[i][jj], z);
                    float h = sig(z);
                    hv[jj] = h; dv[jj] = h - h * h;
                }
                const int ktl = k8l >> 2, kq = k8l & 3, sw = ktl; // sw = (k8>>2)&7
                const int rr0 = s * 8;
                st_pack4(&sA[((rr0 >> 4) * 8 + ktl) * 512 + ((kq * 16 + (rr0 & 15)) ^ sw) * 8 + jh * 4],
                         hv[0], hv[1], hv[2], hv[3]);
                #pragma unroll
                for (int i = 0; i < 7; i++) {
                    const int rr = rr0 + 1 + i;
                    st_pack4(&sA[((rr >> 4) * 8 + ktl) * 512 + ((kq * 16 + (rr & 15)) ^ sw) * 8 + jh * 4],
                             dv[0] * w0v[i][0], dv[1] * w0v[i][1], dv[2] * w0v[i][2], dv[3] * w0v[i][3]);
                }
            }
            __syncthreads();

            // ---- layer 1 MFMA over this K-half, 2 ct-passes of 4, 3-buf rotation ----
            #pragma unroll
            for (int cp = 0; cp < 2; ++cp) {
                const int cp4 = cp * 4;
                PLD(b0, 0); PLD(b1, 1); PLD(b2, 2);
                __builtin_amdgcn_s_setprio(1);
                PST(b0, 0); PLD(b0, 3);
                PST(b1, 1); PLD(b1, 4);
                PST(b2, 2); PLD(b2, 5);
                PST(b0, 3); PLD(b0, 6);
                PST(b1, 4); PLD(b1, 7);
                PST(b2, 5);
                PST(b0, 6);
                PST(b1, 7);
                __builtin_amdgcn_s_setprio(0);
            }
            if (hh == 0) __syncthreads();   // drain reads before half-1 overwrites sA
        }
#undef PLD
#undef PST

        float ep[2][4][3];
        #pragma unroll
        for (int a = 0; a < 2; a++) for (int b = 0; b < 4; b++) for (int c = 0; c < 3; c++) ep[a][b][c] = 0.f;

        #pragma unroll
        for (int ct = 0; ct < 8; ++ct) {
            const int n = w * 128 + ct * 16 + col;
            const float b1n = sU.p.B1[n];
            const float w20 = sU.p.W2[n * 3], w21 = sU.p.W2[n * 3 + 1], w22 = sU.p.W2[n * 3 + 2];
            #pragma unroll
            for (int rt = 0; rt < 2; ++rt) {
                float z2c = __shfl(acc[rt][ct][0], srcl);
                float h2 = sig(z2c + b1n);
                float d2 = h2 - h2 * h2;
                #pragma unroll
                for (int r = 0; r < 4; ++r) {
                    float gg = ((quad & 1) == 0 && r == 0) ? h2 : d2 * acc[rt][ct][r];
                    ep[rt][r][0] = fmaf(gg, w20, ep[rt][r][0]);
                    ep[rt][r][1] = fmaf(gg, w21, ep[rt][r][1]);
                    ep[rt][r][2] = fmaf(gg, w22, ep[rt][r][2]);
                }
            }
        }

        #pragma unroll
        for (int mask = 1; mask <= 8; mask <<= 1)
            #pragma unroll
            for (int a = 0; a < 2; a++)
                #pragma unroll
                for (int b = 0; b < 4; b++)
                    #pragma unroll
                    for (int c = 0; c < 3; c++)
                        ep[a][b][c] += __shfl_xor(ep[a][b][c], mask);
        if (col == 0) {
            #pragma unroll
            for (int rt = 0; rt < 2; ++rt)
                #pragma unroll
                for (int r = 0; r < 4; ++r) {
                    int row = rt * 16 + quad * 4 + r;
                    sU.p.Acc[w][row][0] = ep[rt][r][0];
                    sU.p.Acc[w][row][1] = ep[rt][r][1];
                    sU.p.Acc[w][row][2] = ep[rt][r][2];
                }
        }
        __syncthreads();

        if (tid < 96) {
            int row = tid / 3, j = tid % 3;
            float v = sU.p.Acc[0][row][j] + sU.p.Acc[1][row][j] + sU.p.Acc[2][row][j] + sU.p.Acc[3][row][j];
            int s = row >> 3, i = row & 7;
            size_t M = m0 + s;
            if (i == 0) { v += pb2[j]; out[M * 18 + j] = v; out[OUTA + M * 6 + j] = v; }
            else        { out[JTOT + M * 63 + j * 7 + (i - 1)] = v;
                          out[JANG + M * 42 + j * 7 + (i - 1)] = v; }
            sU.p.Sum[row][j] = v;
        }
        __syncthreads();
        if (tid < 12) {
            int s = tid / 3, j = tid % 3;
            float vel = 0.f;
            #pragma unroll
            for (int i = 0; i < 7; i++) vel = fmaf(sU.p.Sum[s * 8 + 1 + i][j], sU.p.Qd[s][i], vel);
            out[(size_t)(m0 + s) * 18 + 9 + j] = vel;
        }
    } else {
        // ============ RPY: 7 -> 256 -> 256 -> 2, 8 samples (64 rows) ============
        const int h = r5 - 2;
        const int m0 = o * 8;
        const float* W0 = (h == 0) ? rW0_ : (h == 1) ? piW0 : yW0;
        const float* b0p = (h == 0) ? rb0_ : (h == 1) ? pib0 : yb0;
        const float* b1p = (h == 0) ? rb1_ : (h == 1) ? pib1 : yb1;
        const float* W2 = (h == 0) ? rW2_ : (h == 1) ? piW2 : yW2;
        const float* b2p = (h == 0) ? rb2_ : (h == 1) ? pib2 : yb2;
        const unsigned short* wsW1 = wsBase + 262144 + h * 65536;

        if (tid < 256) { sU.r.B0[tid] = b0p[tid]; sU.r.B1[tid] = b1p[tid]; }
        for (int i = tid; i < 512; i += 256) sU.r.W2[i] = W2[i];
        if (tid < 112) {
            int m = tid / 14, c = tid % 14;
            float v = x[(m0 + m) * 14 + c];
            if (c < 7) sU.r.Q[m][c] = v; else sU.r.Qd[m][c - 7] = v;
        }
        __syncthreads();

        const float4* W04 = (const float4*)W0;

        floatx4 acc[4][4];
        #pragma unroll
        for (int rt = 0; rt < 4; rt++)
            #pragma unroll
            for (int ct = 0; ct < 4; ct++) acc[rt][ct] = z4;

        const short8* bbase = (const short8*)wsW1 + (size_t)(w * 4 * 8) * 64 + lane;
        short8 b0[2], b1[2], b2[2];

#define RLD(B, KT) { \
            B[0] = bbase[((cp2 + 0) * 8 + hh4 + (KT)) * 64]; \
            B[1] = bbase[((cp2 + 1) * 8 + hh4 + (KT)) * 64]; }
#define RST(B, KT) { \
            const int sw_ = hh4 + (KT); \
            const short8 a0 = *(const short8*)&sA[(0 * 4 + (KT)) * 512 + (lane ^ sw_) * 8]; \
            const short8 a1 = *(const short8*)&sA[(1 * 4 + (KT)) * 512 + (lane ^ sw_) * 8]; \
            const short8 a2 = *(const short8*)&sA[(2 * 4 + (KT)) * 512 + (lane ^ sw_) * 8]; \
            const short8 a3 = *(const short8*)&sA[(3 * 4 + (KT)) * 512 + (lane ^ sw_) * 8]; \
            acc[0][cp2 + 0] = __builtin_amdgcn_mfma_f32_16x16x32_bf16(a0, B[0], acc[0][cp2 + 0], 0, 0, 0); \
            acc[1][cp2 + 0] = __builtin_amdgcn_mfma_f32_16x16x32_bf16(a1, B[0], acc[1][cp2 + 0], 0, 0, 0); \
            acc[2][cp2 + 0] = __builtin_amdgcn_mfma_f32_16x16x32_bf16(a2, B[0], acc[2][cp2 + 0], 0, 0, 0); \
            acc[3][cp2 + 0] = __builtin_amdgcn_mfma_f32_16x16x32_bf16(a3, B[0], acc[3][cp2 + 0], 0, 0, 0); \
            acc[0][cp2 + 1] = __builtin_amdgcn_mfma_f32_16x16x32_bf16(a0, B[1], acc[0][cp2 + 1], 0, 0, 0); \
            acc[1][cp2 + 1] = __builtin_amdgcn_mfma_f32_16x16x32_bf16(a1, B[1], acc[1][cp2 + 1], 0, 0, 0); \
            acc[2][cp2 + 1] = __builtin_amdgcn_mfma_f32_16x16x32_bf16(a2, B[1], acc[2][cp2 + 1], 0, 0, 0); \
            acc[3][cp2 + 1] = __builtin_amdgcn_mfma_f32_16x16x32_bf16(a3, B[1], acc[3][cp2 + 1], 0, 0, 0); }

        #pragma unroll
        for (int hh = 0; hh < 2; ++hh) {
            const int hh4 = hh * 4;
            // ---- layer 0, K-half hh: 256 threads = 8 samples x 16 k8 x 2 jj-halves ----
            {
                const int jh = tid & 1, item = tid >> 1;
                const int s = item >> 4, k8l = item & 15, k8 = (hh << 4) | k8l;
                float q[7], w0v[7][4];
                #pragma unroll
                for (int i = 0; i < 7; i++) {
                    q[i] = sU.r.Q[s][i];
                    float4 a = W04[i * 64 + k8 * 2 + jh];
                    w0v[i][0] = a.x; w0v[i][1] = a.y; w0v[i][2] = a.z; w0v[i][3] = a.w;
                }
                float hv[4], dv[4];
                #pragma unroll
                for (int jj = 0; jj < 4; jj++) {
                    float z = sU.r.B0[k8 * 8 + jh * 4 + jj];
                    #pragma unroll
                    for (int i = 0; i < 7; i++) z = fmaf(q[i], w0v[i][jj], z);
                    float hhh = sig(z);
                    hv[jj] = hhh; dv[jj] = hhh - hhh * hhh;
                }
                const int ktl = k8l >> 2, kq = k8l & 3;
                const int sw = (hh << 2) | ktl;              // global kt & 7
                const int rr0 = s * 8;
                st_pack4(&sA[((rr0 >> 4) * 4 + ktl) * 512 + ((kq * 16 + (rr0 & 15)) ^ sw) * 8 + jh * 4],
                         hv[0], hv[1], hv[2], hv[3]);
                #pragma unroll
                for (int i = 0; i < 7; i++) {
                    const int rr = rr0 + 1 + i;
                    st_pack4(&sA[((rr >> 4) * 4 + ktl) * 512 + ((kq * 16 + (rr & 15)) ^ sw) * 8 + jh * 4],
                             dv[0] * w0v[i][0], dv[1] * w0v[i][1], dv[2] * w0v[i][2], dv[3] * w0v[i][3]);
                }
            }
            __syncthreads();

            // ---- layer 1 MFMA over this K-half, 2 ct-passes of 2, 3-buf rotation ----
            #pragma unroll
            for (int cp = 0; cp < 2; ++cp) {
                const int cp2 = cp * 2;
                RLD(b0, 0); RLD(b1, 1); RLD(b2, 2);
                __builtin_amdgcn_s_setprio(1);
                RST(b0, 0); RLD(b0, 3);
                RST(b1, 1);
                RST(b2, 2);
                RST(b0, 3);
                __builtin_amdgcn_s_setprio(0);
            }
            if (hh == 0) __syncthreads();   // drain reads before half-1 overwrites sA
        }
#undef RLD
#undef RST

        float ep[4][4][2];
        #pragma unroll
        for (int a = 0; a < 4; a++) for (int b = 0; b < 4; b++) for (int c = 0; c < 2; c++) ep[a][b][c] = 0.f;

        #pragma unroll
        for (int ct = 0; ct < 4; ++ct) {
            const int n = w * 64 + ct * 16 + col;
            const float b1n = sU.r.B1[n];
            const float w20 = sU.r.W2[n * 2], w21 = sU.r.W2[n * 2 + 1];
            #pragma unroll
            for (int rt = 0; rt < 4; ++rt) {
                float z2c = __shfl(acc[rt][ct][0], srcl);
                float h2 = sig(z2c + b1n);
                float d2 = h2 - h2 * h2;
                #pragma unroll
                for (int r = 0; r < 4; ++r) {
                    float gg = ((quad & 1) == 0 && r == 0) ? h2 : d2 * acc[rt][ct][r];
                    ep[rt][r][0] = fmaf(gg, w20, ep[rt][r][0]);
                    ep[rt][r][1] = fmaf(gg, w21, ep[rt][r][1]);
                }
            }
        }

        #pragma unroll
        for (int mask = 1; mask <= 8; mask <<= 1)
            #pragma unroll
            for (int a = 0; a < 4; a++)
                #pragma unroll
                for (int b = 0; b < 4; b++)
                    #pragma unroll
                    for (int c = 0; c < 2; c++)
                        ep[a][b][c] += __shfl_xor(ep[a][b][c], mask);
        if (col == 0) {
            #pragma unroll
            for (int rt = 0; rt < 4; ++rt)
                #pragma unroll
                for (int r = 0; r < 4; ++r) {
                    int row = rt * 16 + quad * 4 + r;
                    sU.r.Acc[w][row][0] = ep[rt][r][0];
                    sU.r.Acc[w][row][1] = ep[rt][r][1];
                }
        }
        __syncthreads();

        if (tid < 128) {
            int row = tid >> 1, j = tid & 1;
            float v = sU.r.Acc[0][row][j] + sU.r.Acc[1][row][j] + sU.r.Acc[2][row][j] + sU.r.Acc[3][row][j];
            if ((row & 7) == 0) v += b2p[j];
            sU.r.Sum[row][j] = v;
        }
        __syncthreads();

        if (tid < 8) {
            int s = tid;
            size_t M = m0 + s;
            float y0 = sU.r.Sum[s * 8][0], y1 = sU.r.Sum[s * 8][1];
            float sv = sinf(y0), cv = cosf(y1);
            out[M * 18 + 3 + h] = sv;
            out[M * 18 + 6 + h] = cv;
            out[OUTA + M * 6 + 3 + h] = atan2f(sv, cv);
            float f0 = cosf(y0), f1 = -sinf(y1);
            float inv = 1.0f / fmaf(sv, sv, cv * cv);
            float v0 = 0.f, v1 = 0.f;
            #pragma unroll
            for (int i = 0; i < 7; i++) {
                float r0 = f0 * sU.r.Sum[s * 8 + 1 + i][0];
                float r1 = f1 * sU.r.Sum[s * 8 + 1 + i][1];
                out[JTOT + M * 63 + (3 + h) * 7 + i] = r0;
                out[JTOT + M * 63 + (6 + h) * 7 + i] = r1;
                out[JANG + M * 42 + (3 + h) * 7 + i] = (cv * r0 - sv * r1) * inv;
                v0 = fmaf(r0, sU.r.Qd[s][i], v0);
                v1 = fmaf(r1, sU.r.Qd[s][i], v1);
            }
            out[M * 18 + 12 + h] = v0;
            out[M * 18 + 15 + h] = v1;
        }
    }
}

extern "C" void kernel_launch(void* const* d_in, const int* in_sizes, int n_in,
                              void* d_out, int out_size, void* d_ws, size_t ws_size,
                              hipStream_t stream) {
    (void)n_in; (void)out_size; (void)ws_size;
    const float* x = (const float*)d_in[0];
    float* out = (float*)d_out;
    unsigned short* ws = (unsigned short*)d_ws;
    const int ns = in_sizes[0] / 14;

    convert_all<<<dim3(1792), 256, 0, stream>>>(
        (const float*)d_in[3], (const float*)d_in[9],
        (const float*)d_in[15], (const float*)d_in[21], ws);

    // 10240 blocks (2048 octets x 5 roles); 16KB dynamic LDS
    fused_mfma<<<dim3((ns / 8) * 5), 256, 16384, stream>>>(
        x,
        (const float*)d_in[1],  (const float*)d_in[2],  (const float*)d_in[4],
        (const float*)d_in[5],  (const float*)d_in[6],
        (const float*)d_in[7],  (const float*)d_in[8],  (const float*)d_in[10],
        (const float*)d_in[11], (const float*)d_in[12],
        (const float*)d_in[13], (const float*)d_in[14], (const float*)d_in[16],
        (const float*)d_in[17], (const float*)d_in[18],
        (const float*)d_in[19], (const float*)d_in[20], (const float*)d_in[22],
        (const float*)d_in[23], (const float*)d_in[24],
        ws, out, ns);
}

// Round 5
// 286.646 us; speedup vs baseline: 2.8005x; 1.0715x over previous
//
#include <hip/hip_runtime.h>
#include <math.h>

typedef __attribute__((ext_vector_type(8))) short short8;
typedef __attribute__((ext_vector_type(4))) float floatx4;
typedef __attribute__((ext_vector_type(2))) unsigned uint2v;

__device__ __forceinline__ float sig(float z) { return 1.0f / (1.0f + __expf(-z)); }

__device__ __forceinline__ unsigned short f2bf(float f) {
    unsigned u = __float_as_uint(f);
    u = (u + 0x7FFFu + ((u >> 16) & 1u)) >> 16;   // RNE
    return (unsigned short)u;
}

// v_cvt_pk_bf16_f32: packs 2 f32 -> 2 bf16 (RNE) in one instruction.
__device__ __forceinline__ unsigned cvtpk_bf16(float lo, float hi) {
    unsigned r;
    asm("v_cvt_pk_bf16_f32 %0, %1, %2" : "=v"(r) : "v"(lo), "v"(hi));
    return r;
}

// 4 floats -> 4 bf16 (8B store), RNE identical to f2bf.
__device__ __forceinline__ void st_pack4(unsigned short* p, float v0, float v1, float v2, float v3) {
    uint2v u;
    u.x = cvtpk_bf16(v0, v1);
    u.y = cvtpk_bf16(v2, v3);
    *(uint2v*)p = u;
}

// All four W1 matrices -> bf16 pre-swizzled MFMA 16x16x32 B-frag order.
// blk = (n>>4)*(H/32) + (k>>5), lane = ((k>>3)&3)*16 + (n&15), j = k&7.
__global__ void convert_all(const float* __restrict__ s0, const float* __restrict__ s1,
                            const float* __restrict__ s2, const float* __restrict__ s3,
                            unsigned short* __restrict__ ws) {
    int idx = blockIdx.x * 256 + threadIdx.x;          // 0 .. 458751
    const float* src; unsigned short* dst; int H, logH, local;
    if (idx < 262144) { src = s0; dst = ws; H = 512; logH = 9; local = idx; }
    else {
        int r = idx - 262144; int m = r >> 16; local = r & 65535;
        H = 256; logH = 8;
        src = (m == 0) ? s1 : (m == 1) ? s2 : s3;
        dst = ws + 262144 + m * 65536;
    }
    int n = local & (H - 1), k = local >> logH;
    int KT = H >> 5;
    int blk = (n >> 4) * KT + (k >> 5);
    int lane = ((k >> 3) & 3) * 16 + (n & 15);
    int j = k & 7;
    dst[(blk * 64 + lane) * 8 + j] = f2bf(src[local]);
}

// R5 (on R4's 247.8us base; R4 post-mortem: MFMA-busy ~54us = analytic floor,
// VALU-busy ~91us, ~100us both-idle -> epilogue DS-pipe chains are the slack):
//  - Epilogue butterfly reduce (96-128 ds_bpermute/thread, 16x redundant)
//    replaced by LDS-transpose reduce: partials -> sA f32 [w][row][j][17],
//    barrier, 96/128 threads sum 64 partials each. Removes ~400 DS ops/wave.
//  - Acc[] cross-wave staging folded into the same pass (static LDS -11.9KB ->
//    10.9KB); dynamic LDS 16 -> 34KB (rpy partials). 45.7KB/block = 3 blocks/CU.
//  - Sum order over (col,w) now sequential (was butterfly): ~1ulp f32 change.
struct PosS {
    float B0[512], B1[512], W2[1536];
    float Q[4][8], Qd[4][8];
    float Sum[32][3];
};
struct RpyS {
    float B0[256], B1[256], W2[512];
    float Q[8][8], Qd[8][8];
    float Sum[64][2];
};

__global__ __launch_bounds__(256, 3)
void fused_mfma(const float* __restrict__ x,
                const float* __restrict__ pW0, const float* __restrict__ pb0,
                const float* __restrict__ pb1,
                const float* __restrict__ pW2, const float* __restrict__ pb2,
                const float* __restrict__ rW0_, const float* __restrict__ rb0_,
                const float* __restrict__ rb1_,
                const float* __restrict__ rW2_, const float* __restrict__ rb2_,
                const float* __restrict__ piW0, const float* __restrict__ pib0,
                const float* __restrict__ pib1,
                const float* __restrict__ piW2, const float* __restrict__ pib2,
                const float* __restrict__ yW0, const float* __restrict__ yb0,
                const float* __restrict__ yb1,
                const float* __restrict__ yW2, const float* __restrict__ yb2,
                const unsigned short* __restrict__ wsBase,
                float* __restrict__ out, int ns)
{
    extern __shared__ unsigned short sA[];      // 34816B: A-tile (16KB) then f32 partials
    __shared__ union { PosS p; RpyS r; } sU;

    const int tid = threadIdx.x;
    const int xcd  = blockIdx.x & 7;
    const int slot = blockIdx.x >> 3;           // 0..1279 within this XCD
    const int o_l  = slot / 5, r5 = slot % 5;
    const int o = xcd + (o_l << 3);             // sample-octet 0..2047

    const size_t JTOT = (size_t)ns * 18, OUTA = (size_t)ns * 81, JANG = (size_t)ns * 87;
    const floatx4 z4 = {0.f, 0.f, 0.f, 0.f};
    const int w = tid >> 6, lane = tid & 63;
    const int quad = lane >> 4, col = lane & 15;
    const int srcl = lane & 47;

    if (r5 < 2) {
        // ============ POS: 7 -> 512 -> 512 -> 3, 4 samples (32 rows) ============
        const int m0 = (o * 2 + r5) * 4;
        const unsigned short* wsW1 = wsBase;

        for (int i = tid; i < 512;  i += 256) { sU.p.B0[i] = pb0[i]; sU.p.B1[i] = pb1[i]; }
        for (int i = tid; i < 1536; i += 256) sU.p.W2[i] = pW2[i];
        if (tid < 56) {
            int m = tid / 14, c = tid % 14;
            float v = x[(m0 + m) * 14 + c];
            if (c < 7) sU.p.Q[m][c] = v; else sU.p.Qd[m][c - 7] = v;
        }
        __syncthreads();

        const float4* W04 = (const float4*)pW0;

        floatx4 acc[2][8];
        #pragma unroll
        for (int rt = 0; rt < 2; rt++)
            #pragma unroll
            for (int ct = 0; ct < 8; ct++) acc[rt][ct] = z4;

        const short8* bbase = (const short8*)wsW1 + (size_t)(w * 8 * 16) * 64 + lane;
        short8 b0[4], b1[4], b2[4];

#define PLD(B, KT) { \
            B[0] = bbase[((cp4 + 0) * 16 + hh8 + (KT)) * 64]; \
            B[1] = bbase[((cp4 + 1) * 16 + hh8 + (KT)) * 64]; \
            B[2] = bbase[((cp4 + 2) * 16 + hh8 + (KT)) * 64]; \
            B[3] = bbase[((cp4 + 3) * 16 + hh8 + (KT)) * 64]; }
#define PST(B, KT) { \
            const short8 a0 = *(const short8*)&sA[(0 * 8 + (KT)) * 512 + (lane ^ (KT)) * 8]; \
            const short8 a1 = *(const short8*)&sA[(1 * 8 + (KT)) * 512 + (lane ^ (KT)) * 8]; \
            acc[0][cp4 + 0] = __builtin_amdgcn_mfma_f32_16x16x32_bf16(a0, B[0], acc[0][cp4 + 0], 0, 0, 0); \
            acc[1][cp4 + 0] = __builtin_amdgcn_mfma_f32_16x16x32_bf16(a1, B[0], acc[1][cp4 + 0], 0, 0, 0); \
            acc[0][cp4 + 1] = __builtin_amdgcn_mfma_f32_16x16x32_bf16(a0, B[1], acc[0][cp4 + 1], 0, 0, 0); \
            acc[1][cp4 + 1] = __builtin_amdgcn_mfma_f32_16x16x32_bf16(a1, B[1], acc[1][cp4 + 1], 0, 0, 0); \
            acc[0][cp4 + 2] = __builtin_amdgcn_mfma_f32_16x16x32_bf16(a0, B[2], acc[0][cp4 + 2], 0, 0, 0); \
            acc[1][cp4 + 2] = __builtin_amdgcn_mfma_f32_16x16x32_bf16(a1, B[2], acc[1][cp4 + 2], 0, 0, 0); \
            acc[0][cp4 + 3] = __builtin_amdgcn_mfma_f32_16x16x32_bf16(a0, B[3], acc[0][cp4 + 3], 0, 0, 0); \
            acc[1][cp4 + 3] = __builtin_amdgcn_mfma_f32_16x16x32_bf16(a1, B[3], acc[1][cp4 + 3], 0, 0, 0); }

        #pragma unroll
        for (int hh = 0; hh < 2; ++hh) {
            const int hh8 = hh * 8;
            // ---- layer 0, K-half hh: 256 threads = 4 samples x 32 k8 x 2 jj-halves ----
            {
                const int jh = tid & 1, item = tid >> 1;
                const int s = item >> 5, k8l = item & 31, k8 = (hh << 5) | k8l;
                float q[7], w0v[7][4];
                #pragma unroll
                for (int i = 0; i < 7; i++) {
                    q[i] = sU.p.Q[s][i];
                    float4 a = W04[i * 128 + k8 * 2 + jh];
                    w0v[i][0] = a.x; w0v[i][1] = a.y; w0v[i][2] = a.z; w0v[i][3] = a.w;
                }
                float hv[4], dv[4];
                #pragma unroll
                for (int jj = 0; jj < 4; jj++) {
                    float z = sU.p.B0[k8 * 8 + jh * 4 + jj];
                    #pragma unroll
                    for (int i = 0; i < 7; i++) z = fmaf(q[i], w0v[i][jj], z);
                    float h = sig(z);
                    hv[jj] = h; dv[jj] = h - h * h;
                }
                const int ktl = k8l >> 2, kq = k8l & 3, sw = ktl; // sw = (k8>>2)&7
                const int rr0 = s * 8;
                st_pack4(&sA[((rr0 >> 4) * 8 + ktl) * 512 + ((kq * 16 + (rr0 & 15)) ^ sw) * 8 + jh * 4],
                         hv[0], hv[1], hv[2], hv[3]);
                #pragma unroll
                for (int i = 0; i < 7; i++) {
                    const int rr = rr0 + 1 + i;
                    st_pack4(&sA[((rr >> 4) * 8 + ktl) * 512 + ((kq * 16 + (rr & 15)) ^ sw) * 8 + jh * 4],
                             dv[0] * w0v[i][0], dv[1] * w0v[i][1], dv[2] * w0v[i][2], dv[3] * w0v[i][3]);
                }
            }
            __syncthreads();

            // ---- layer 1 MFMA over this K-half, 2 ct-passes of 4, 3-buf rotation ----
            #pragma unroll
            for (int cp = 0; cp < 2; ++cp) {
                const int cp4 = cp * 4;
                PLD(b0, 0); PLD(b1, 1); PLD(b2, 2);
                __builtin_amdgcn_s_setprio(1);
                PST(b0, 0); PLD(b0, 3);
                PST(b1, 1); PLD(b1, 4);
                PST(b2, 2); PLD(b2, 5);
                PST(b0, 3); PLD(b0, 6);
                PST(b1, 4); PLD(b1, 7);
                PST(b2, 5);
                PST(b0, 6);
                PST(b1, 7);
                __builtin_amdgcn_s_setprio(0);
            }
            if (hh == 0) __syncthreads();   // drain reads before half-1 overwrites sA
        }
#undef PLD
#undef PST

        float ep[2][4][3];
        #pragma unroll
        for (int a = 0; a < 2; a++) for (int b = 0; b < 4; b++) for (int c = 0; c < 3; c++) ep[a][b][c] = 0.f;

        #pragma unroll
        for (int ct = 0; ct < 8; ++ct) {
            const int n = w * 128 + ct * 16 + col;
            const float b1n = sU.p.B1[n];
            const float w20 = sU.p.W2[n * 3], w21 = sU.p.W2[n * 3 + 1], w22 = sU.p.W2[n * 3 + 2];
            #pragma unroll
            for (int rt = 0; rt < 2; ++rt) {
                float z2c = __shfl(acc[rt][ct][0], srcl);
                float h2 = sig(z2c + b1n);
                float d2 = h2 - h2 * h2;
                #pragma unroll
                for (int r = 0; r < 4; ++r) {
                    float gg = ((quad & 1) == 0 && r == 0) ? h2 : d2 * acc[rt][ct][r];
                    ep[rt][r][0] = fmaf(gg, w20, ep[rt][r][0]);
                    ep[rt][r][1] = fmaf(gg, w21, ep[rt][r][1]);
                    ep[rt][r][2] = fmaf(gg, w22, ep[rt][r][2]);
                }
            }
        }

        // LDS-transpose reduce: partials [w][row][j][17] f32 in sA
        __syncthreads();                        // all waves done reading A-tile
        {
            float* pl = (float*)sA;
            #pragma unroll
            for (int rt = 0; rt < 2; ++rt)
                #pragma unroll
                for (int r = 0; r < 4; ++r) {
                    int row = rt * 16 + quad * 4 + r;
                    int base = ((w * 32 + row) * 3) * 17 + col;
                    pl[base]      = ep[rt][r][0];
                    pl[base + 17] = ep[rt][r][1];
                    pl[base + 34] = ep[rt][r][2];
                }
        }
        __syncthreads();

        if (tid < 96) {
            const float* pl = (const float*)sA;
            int row = tid / 3, j = tid % 3;
            float v = 0.f;
            #pragma unroll
            for (int ww = 0; ww < 4; ++ww) {
                const float* q = &pl[((ww * 32 + row) * 3 + j) * 17];
                #pragma unroll
                for (int c = 0; c < 16; ++c) v += q[c];
            }
            int s = row >> 3, i = row & 7;
            size_t M = m0 + s;
            if (i == 0) { v += pb2[j]; out[M * 18 + j] = v; out[OUTA + M * 6 + j] = v; }
            else        { out[JTOT + M * 63 + j * 7 + (i - 1)] = v;
                          out[JANG + M * 42 + j * 7 + (i - 1)] = v; }
            sU.p.Sum[row][j] = v;
        }
        __syncthreads();
        if (tid < 12) {
            int s = tid / 3, j = tid % 3;
            float vel = 0.f;
            #pragma unroll
            for (int i = 0; i < 7; i++) vel = fmaf(sU.p.Sum[s * 8 + 1 + i][j], sU.p.Qd[s][i], vel);
            out[(size_t)(m0 + s) * 18 + 9 + j] = vel;
        }
    } else {
        // ============ RPY: 7 -> 256 -> 256 -> 2, 8 samples (64 rows) ============
        const int h = r5 - 2;
        const int m0 = o * 8;
        const float* W0 = (h == 0) ? rW0_ : (h == 1) ? piW0 : yW0;
        const float* b0p = (h == 0) ? rb0_ : (h == 1) ? pib0 : yb0;
        const float* b1p = (h == 0) ? rb1_ : (h == 1) ? pib1 : yb1;
        const float* W2 = (h == 0) ? rW2_ : (h == 1) ? piW2 : yW2;
        const float* b2p = (h == 0) ? rb2_ : (h == 1) ? pib2 : yb2;
        const unsigned short* wsW1 = wsBase + 262144 + h * 65536;

        if (tid < 256) { sU.r.B0[tid] = b0p[tid]; sU.r.B1[tid] = b1p[tid]; }
        for (int i = tid; i < 512; i += 256) sU.r.W2[i] = W2[i];
        if (tid < 112) {
            int m = tid / 14, c = tid % 14;
            float v = x[(m0 + m) * 14 + c];
            if (c < 7) sU.r.Q[m][c] = v; else sU.r.Qd[m][c - 7] = v;
        }
        __syncthreads();

        const float4* W04 = (const float4*)W0;

        floatx4 acc[4][4];
        #pragma unroll
        for (int rt = 0; rt < 4; rt++)
            #pragma unroll
            for (int ct = 0; ct < 4; ct++) acc[rt][ct] = z4;

        const short8* bbase = (const short8*)wsW1 + (size_t)(w * 4 * 8) * 64 + lane;
        short8 b0[2], b1[2], b2[2];

#define RLD(B, KT) { \
            B[0] = bbase[((cp2 + 0) * 8 + hh4 + (KT)) * 64]; \
            B[1] = bbase[((cp2 + 1) * 8 + hh4 + (KT)) * 64]; }
#define RST(B, KT) { \
            const int sw_ = hh4 + (KT); \
            const short8 a0 = *(const short8*)&sA[(0 * 4 + (KT)) * 512 + (lane ^ sw_) * 8]; \
            const short8 a1 = *(const short8*)&sA[(1 * 4 + (KT)) * 512 + (lane ^ sw_) * 8]; \
            const short8 a2 = *(const short8*)&sA[(2 * 4 + (KT)) * 512 + (lane ^ sw_) * 8]; \
            const short8 a3 = *(const short8*)&sA[(3 * 4 + (KT)) * 512 + (lane ^ sw_) * 8]; \
            acc[0][cp2 + 0] = __builtin_amdgcn_mfma_f32_16x16x32_bf16(a0, B[0], acc[0][cp2 + 0], 0, 0, 0); \
            acc[1][cp2 + 0] = __builtin_amdgcn_mfma_f32_16x16x32_bf16(a1, B[0], acc[1][cp2 + 0], 0, 0, 0); \
            acc[2][cp2 + 0] = __builtin_amdgcn_mfma_f32_16x16x32_bf16(a2, B[0], acc[2][cp2 + 0], 0, 0, 0); \
            acc[3][cp2 + 0] = __builtin_amdgcn_mfma_f32_16x16x32_bf16(a3, B[0], acc[3][cp2 + 0], 0, 0, 0); \
            acc[0][cp2 + 1] = __builtin_amdgcn_mfma_f32_16x16x32_bf16(a0, B[1], acc[0][cp2 + 1], 0, 0, 0); \
            acc[1][cp2 + 1] = __builtin_amdgcn_mfma_f32_16x16x32_bf16(a1, B[1], acc[1][cp2 + 1], 0, 0, 0); \
            acc[2][cp2 + 1] = __builtin_amdgcn_mfma_f32_16x16x32_bf16(a2, B[1], acc[2][cp2 + 1], 0, 0, 0); \
            acc[3][cp2 + 1] = __builtin_amdgcn_mfma_f32_16x16x32_bf16(a3, B[1], acc[3][cp2 + 1], 0, 0, 0); }

        #pragma unroll
        for (int hh = 0; hh < 2; ++hh) {
            const int hh4 = hh * 4;
            // ---- layer 0, K-half hh: 256 threads = 8 samples x 16 k8 x 2 jj-halves ----
            {
                const int jh = tid & 1, item = tid >> 1;
                const int s = item >> 4, k8l = item & 15, k8 = (hh << 4) | k8l;
                float q[7], w0v[7][4];
                #pragma unroll
                for (int i = 0; i < 7; i++) {
                    q[i] = sU.r.Q[s][i];
                    float4 a = W04[i * 64 + k8 * 2 + jh];
                    w0v[i][0] = a.x; w0v[i][1] = a.y; w0v[i][2] = a.z; w0v[i][3] = a.w;
                }
                float hv[4], dv[4];
                #pragma unroll
                for (int jj = 0; jj < 4; jj++) {
                    float z = sU.r.B0[k8 * 8 + jh * 4 + jj];
                    #pragma unroll
                    for (int i = 0; i < 7; i++) z = fmaf(q[i], w0v[i][jj], z);
                    float hhh = sig(z);
                    hv[jj] = hhh; dv[jj] = hhh - hhh * hhh;
                }
                const int ktl = k8l >> 2, kq = k8l & 3;
                const int sw = (hh << 2) | ktl;              // global kt & 7
                const int rr0 = s * 8;
                st_pack4(&sA[((rr0 >> 4) * 4 + ktl) * 512 + ((kq * 16 + (rr0 & 15)) ^ sw) * 8 + jh * 4],
                         hv[0], hv[1], hv[2], hv[3]);
                #pragma unroll
                for (int i = 0; i < 7; i++) {
                    const int rr = rr0 + 1 + i;
                    st_pack4(&sA[((rr >> 4) * 4 + ktl) * 512 + ((kq * 16 + (rr & 15)) ^ sw) * 8 + jh * 4],
                             dv[0] * w0v[i][0], dv[1] * w0v[i][1], dv[2] * w0v[i][2], dv[3] * w0v[i][3]);
                }
            }
            __syncthreads();

            // ---- layer 1 MFMA over this K-half, 2 ct-passes of 2, 3-buf rotation ----
            #pragma unroll
            for (int cp = 0; cp < 2; ++cp) {
                const int cp2 = cp * 2;
                RLD(b0, 0); RLD(b1, 1); RLD(b2, 2);
                __builtin_amdgcn_s_setprio(1);
                RST(b0, 0); RLD(b0, 3);
                RST(b1, 1);
                RST(b2, 2);
                RST(b0, 3);
                __builtin_amdgcn_s_setprio(0);
            }
            if (hh == 0) __syncthreads();   // drain reads before half-1 overwrites sA
        }
#undef RLD
#undef RST

        float ep[4][4][2];
        #pragma unroll
        for (int a = 0; a < 4; a++) for (int b = 0; b < 4; b++) for (int c = 0; c < 2; c++) ep[a][b][c] = 0.f;

        #pragma unroll
        for (int ct = 0; ct < 4; ++ct) {
            const int n = w * 64 + ct * 16 + col;
            const float b1n = sU.r.B1[n];
            const float w20 = sU.r.W2[n * 2], w21 = sU.r.W2[n * 2 + 1];
            #pragma unroll
            for (int rt = 0; rt < 4; ++rt) {
                float z2c = __shfl(acc[rt][ct][0], srcl);
                float h2 = sig(z2c + b1n);
                float d2 = h2 - h2 * h2;
                #pragma unroll
                for (int r = 0; r < 4; ++r) {
                    float gg = ((quad & 1) == 0 && r == 0) ? h2 : d2 * acc[rt][ct][r];
                    ep[rt][r][0] = fmaf(gg, w20, ep[rt][r][0]);
                    ep[rt][r][1] = fmaf(gg, w21, ep[rt][r][1]);
                }
            }
        }

        // LDS-transpose reduce: partials [w][row][j][17] f32 in sA
        __syncthreads();                        // all waves done reading A-tile
        {
            float* pl = (float*)sA;
            #pragma unroll
            for (int rt = 0; rt < 4; ++rt)
                #pragma unroll
                for (int r = 0; r < 4; ++r) {
                    int row = rt * 16 + quad * 4 + r;
                    int base = ((w * 64 + row) * 2) * 17 + col;
                    pl[base]      = ep[rt][r][0];
                    pl[base + 17] = ep[rt][r][1];
                }
        }
        __syncthreads();

        if (tid < 128) {
            const float* pl = (const float*)sA;
            int row = tid >> 1, j = tid & 1;
            float v = 0.f;
            #pragma unroll
            for (int ww = 0; ww < 4; ++ww) {
                const float* q = &pl[((ww * 64 + row) * 2 + j) * 17];
                #pragma unroll
                for (int c = 0; c < 16; ++c) v += q[c];
            }
            if ((row & 7) == 0) v += b2p[j];
            sU.r.Sum[row][j] = v;
        }
        __syncthreads();

        if (tid < 8) {
            int s = tid;
            size_t M = m0 + s;
            float y0 = sU.r.Sum[s * 8][0], y1 = sU.r.Sum[s * 8][1];
            float sv = sinf(y0), cv = cosf(y1);
            out[M * 18 + 3 + h] = sv;
            out[M * 18 + 6 + h] = cv;
            out[OUTA + M * 6 + 3 + h] = atan2f(sv, cv);
            float f0 = cosf(y0), f1 = -sinf(y1);
            float inv = 1.0f / fmaf(sv, sv, cv * cv);
            float v0 = 0.f, v1 = 0.f;
            #pragma unroll
            for (int i = 0; i < 7; i++) {
                float r0 = f0 * sU.r.Sum[s * 8 + 1 + i][0];
                float r1 = f1 * sU.r.Sum[s * 8 + 1 + i][1];
                out[JTOT + M * 63 + (3 + h) * 7 + i] = r0;
                out[JTOT + M * 63 + (6 + h) * 7 + i] = r1;
                out[JANG + M * 42 + (3 + h) * 7 + i] = (cv * r0 - sv * r1) * inv;
                v0 = fmaf(r0, sU.r.Qd[s][i], v0);
                v1 = fmaf(r1, sU.r.Qd[s][i], v1);
            }
            out[M * 18 + 12 + h] = v0;
            out[M * 18 + 15 + h] = v1;
        }
    }
}

extern "C" void kernel_launch(void* const* d_in, const int* in_sizes, int n_in,
                              void* d_out, int out_size, void* d_ws, size_t ws_size,
                              hipStream_t stream) {
    (void)n_in; (void)out_size; (void)ws_size;
    const float* x = (const float*)d_in[0];
    float* out = (float*)d_out;
    unsigned short* ws = (unsigned short*)d_ws;
    const int ns = in_sizes[0] / 14;

    convert_all<<<dim3(1792), 256, 0, stream>>>(
        (const float*)d_in[3], (const float*)d_in[9],
        (const float*)d_in[15], (const float*)d_in[21], ws);

    // 10240 blocks (2048 octets x 5 roles); 34816B dynamic LDS
    // (16KB A-tile phase, then f32 reduce partials: rpy 4*64*2*17*4 = 34816B)
    fused_mfma<<<dim3((ns / 8) * 5), 256, 34816, stream>>>(
        x,
        (const float*)d_in[1],  (const float*)d_in[2],  (const float*)d_in[4],
        (const float*)d_in[5],  (const float*)d_in[6],
        (const float*)d_in[7],  (const float*)d_in[8],  (const float*)d_in[10],
        (const float*)d_in[11], (const float*)d_in[12],
        (const float*)d_in[13], (const float*)d_in[14], (const float*)d_in[16],
        (const float*)d_in[17], (const float*)d_in[18],
        (const float*)d_in[19], (const float*)d_in[20], (const float*)d_in[22],
        (const float*)d_in[23], (const float*)d_in[24],
        ws, out, ns);
}